// Round 1
// baseline (178.663 us; speedup 1.0000x reference)
//
#include <hip/hip_runtime.h>

#define GN_EPS 1e-8f

static constexpr int F   = 64;   // features
static constexpr int G   = 8;    // groups (group of channel f is f % 8 due to reshape(-1, G))
static constexpr int NB  = 16;   // batches
static constexpr int BLK = 256;
static constexpr int GRID1 = 1024;
static constexpr int GRID2 = 1024;

// --- Kernel A: per-batch row offsets via binary search (ids are sorted) ---
__global__ void gn_offsets(const int* __restrict__ ids, int n, int* __restrict__ off) {
    int b = threadIdx.x;
    if (b > NB) return;
    int lo = 0, hi = n;
    while (lo < hi) {
        int mid = (lo + hi) >> 1;
        if (ids[mid] < b) lo = mid + 1; else hi = mid;
    }
    off[b] = lo;   // off[b] = first row with id >= b; count_b = off[b+1]-off[b]
}

// --- Kernel B: per-(batch,group) sum and sumsq ---
// Tile: 16 rows x 16 threads/row (float4 each). Lane l: quad = l&15, element j of
// the float4 at feature 4*quad+j belongs to group ( (l&1)*4 + j ).
// Register-accumulate while the wave's batch id run is uniform; on change, butterfly-
// reduce across the wave (XOR 2..32 keeps lane parity = group-half) and LDS-atomic.
__global__ __launch_bounds__(BLK) void gn_stats(
        const float* __restrict__ feats, const int* __restrict__ ids, int n,
        float* __restrict__ gsum, float* __restrict__ gsq) {
    __shared__ __align__(16) float lsum[NB * G];
    __shared__ __align__(16) float lsq [NB * G];
    const int t = threadIdx.x;
    if (t < NB * G) { lsum[t] = 0.f; lsq[t] = 0.f; }
    __syncthreads();

    const int rpb  = (n + (int)gridDim.x - 1) / (int)gridDim.x;
    const int row0 = (int)blockIdx.x * rpb;
    const int row1 = min(n, row0 + rpb);
    const int quad   = t & 15;
    const int subrow = t >> 4;
    const int lane   = t & 63;
    const int gbase  = (t & 1) * 4;

    float s0=0.f,s1=0.f,s2=0.f,s3=0.f,q0=0.f,q1=0.f,q2=0.f,q3=0.f;
    int run_id = -1;

    auto flush = [&](int rid) {
        #pragma unroll
        for (int m = 2; m <= 32; m <<= 1) {
            s0 += __shfl_xor(s0, m); s1 += __shfl_xor(s1, m);
            s2 += __shfl_xor(s2, m); s3 += __shfl_xor(s3, m);
            q0 += __shfl_xor(q0, m); q1 += __shfl_xor(q1, m);
            q2 += __shfl_xor(q2, m); q3 += __shfl_xor(q3, m);
        }
        if (lane < 2) {   // lane0 -> groups 0..3, lane1 -> groups 4..7
            float* ps = &lsum[rid * G + lane * 4];
            float* pq = &lsq [rid * G + lane * 4];
            atomicAdd(ps + 0, s0); atomicAdd(ps + 1, s1);
            atomicAdd(ps + 2, s2); atomicAdd(ps + 3, s3);
            atomicAdd(pq + 0, q0); atomicAdd(pq + 1, q1);
            atomicAdd(pq + 2, q2); atomicAdd(pq + 3, q3);
        }
        s0=s1=s2=s3=q0=q1=q2=q3=0.f;
    };

    for (int base = row0; base < row1; base += 16) {
        const int row   = base + subrow;
        const bool valid = row < row1;
        const int rowc  = valid ? row : row1 - 1;
        const int id    = ids[rowc];
        float4 x;
        if (valid) x = *reinterpret_cast<const float4*>(feats + (size_t)row * F + quad * 4);
        else       x = make_float4(0.f, 0.f, 0.f, 0.f);   // zeros are harmless in sums

        const unsigned long long same = __ballot(id == run_id);
        if (same != ~0ull) {
            if (run_id >= 0) flush(run_id);
            const int first = __shfl(id, 0);
            if (__all(id == first)) {
                run_id = first;
            } else {
                // wave straddles a batch boundary (happens <= B-1 times globally)
                atomicAdd(&lsum[id * G + gbase + 0], x.x);
                atomicAdd(&lsum[id * G + gbase + 1], x.y);
                atomicAdd(&lsum[id * G + gbase + 2], x.z);
                atomicAdd(&lsum[id * G + gbase + 3], x.w);
                atomicAdd(&lsq [id * G + gbase + 0], x.x * x.x);
                atomicAdd(&lsq [id * G + gbase + 1], x.y * x.y);
                atomicAdd(&lsq [id * G + gbase + 2], x.z * x.z);
                atomicAdd(&lsq [id * G + gbase + 3], x.w * x.w);
                run_id = -1;
                continue;
            }
        }
        s0 += x.x; q0 = fmaf(x.x, x.x, q0);
        s1 += x.y; q1 = fmaf(x.y, x.y, q1);
        s2 += x.z; q2 = fmaf(x.z, x.z, q2);
        s3 += x.w; q3 = fmaf(x.w, x.w, q3);
    }
    if (run_id >= 0) flush(run_id);
    __syncthreads();
    if (t < NB * G) {
        atomicAdd(&gsum[t], lsum[t]);
        atomicAdd(&gsq [t], lsq [t]);
    }
}

// --- Kernel C: normalize.  out = x * A[b][f] + C[b][f], tables built per block. ---
__global__ __launch_bounds__(BLK) void gn_norm(
        const float* __restrict__ feats, const int* __restrict__ ids, int n,
        const float* __restrict__ gsum, const float* __restrict__ gsq,
        const int* __restrict__ off,
        const float* __restrict__ gamma, const float* __restrict__ beta,
        float* __restrict__ out) {
    __shared__ __align__(16) float sA[NB * F];
    __shared__ __align__(16) float sC[NB * F];
    const int t = threadIdx.x;
    for (int idx = t; idx < NB * F; idx += BLK) {
        const int b = idx >> 6;
        const int f = idx & 63;
        const int g = f & 7;
        const float cnt  = (float)max((off[b + 1] - off[b]) * (F / G), 1);
        const float mean = gsum[b * G + g] / cnt;
        float var = gsq[b * G + g] / cnt - mean * mean;
        var = fmaxf(var, 0.f);
        const float inv = 1.0f / sqrtf(var + GN_EPS);
        const float ag  = inv * gamma[f];
        sA[idx] = ag;
        sC[idx] = fmaf(-mean, ag, beta[f]);
    }
    __syncthreads();

    const int rpb  = (n + (int)gridDim.x - 1) / (int)gridDim.x;
    const int row0 = (int)blockIdx.x * rpb;
    const int row1 = min(n, row0 + rpb);
    const int quad   = t & 15;
    const int subrow = t >> 4;

    for (int base = row0; base < row1; base += 16) {
        const int row = base + subrow;
        if (row >= row1) continue;
        const int id = ids[row];
        const size_t p = (size_t)row * F + quad * 4;
        const float4 x = *reinterpret_cast<const float4*>(feats + p);
        const float4 a = *reinterpret_cast<const float4*>(&sA[id * F + quad * 4]);
        const float4 c = *reinterpret_cast<const float4*>(&sC[id * F + quad * 4]);
        float4 o;
        o.x = fmaf(x.x, a.x, c.x);
        o.y = fmaf(x.y, a.y, c.y);
        o.z = fmaf(x.z, a.z, c.z);
        o.w = fmaf(x.w, a.w, c.w);
        *reinterpret_cast<float4*>(out + p) = o;
    }
}

extern "C" void kernel_launch(void* const* d_in, const int* in_sizes, int n_in,
                              void* d_out, int out_size, void* d_ws, size_t ws_size,
                              hipStream_t stream) {
    const float* feats = (const float*)d_in[0];
    const int*   ids   = (const int*)  d_in[1];
    const float* gamma = (const float*)d_in[2];
    const float* beta  = (const float*)d_in[3];
    const int n = in_sizes[1];               // N rows (batch_ids count)

    float* gsum = (float*)d_ws;              // [NB*G]
    float* gsq  = gsum + NB * G;             // [NB*G]
    int*   off  = (int*)(gsq + NB * G);      // [NB+1]

    // ws is poisoned 0xAA and never re-poisoned between replays -> zero what we atomically accumulate.
    hipMemsetAsync(d_ws, 0, 2 * NB * G * sizeof(float), stream);
    gn_offsets<<<1, 32, 0, stream>>>(ids, n, off);
    gn_stats  <<<GRID1, BLK, 0, stream>>>(feats, ids, n, gsum, gsq);
    gn_norm   <<<GRID2, BLK, 0, stream>>>(feats, ids, n, gsum, gsq, off, gamma, beta, (float*)d_out);
}

// Round 2
// 163.063 us; speedup vs baseline: 1.0957x; 1.0957x over previous
//
#include <hip/hip_runtime.h>

#define GN_EPS 1e-8f

static constexpr int F    = 64;   // features
static constexpr int G    = 8;    // groups (group of channel f is f & 7 due to reshape(-1, G))
static constexpr int NB   = 16;   // batches
static constexpr int BLK  = 256;
static constexpr int GRID = 2048; // 2048 blocks x 4 waves = 8192 waves = full residency

typedef float f32x4 __attribute__((ext_vector_type(4)));

// --- Kernel A: per-batch row offsets via binary search (ids are sorted) ---
__global__ void gn_offsets(const int* __restrict__ ids, int n, int* __restrict__ off) {
    int b = threadIdx.x;
    if (b > NB) return;
    int lo = 0, hi = n;
    while (lo < hi) {
        int mid = (lo + hi) >> 1;
        if (ids[mid] < b) lo = mid + 1; else hi = mid;
    }
    off[b] = lo;   // off[b] = first row with id >= b; off[0]=0, off[NB]=n
}

// --- Kernel B: per-(batch,group) sum/sumsq, segment-uniform inner loop ---
// Layout: 16 threads/row (float4 each), 16 rows per block-step. Within a wave,
// lanes cover 4 consecutive rows (1 KB contiguous). Element j of lane's float4
// at feature quad*4+j belongs to group (quad&1)*4 + j.
__global__ __launch_bounds__(BLK) void gn_stats(
        const float* __restrict__ feats, const int* __restrict__ off_g, int n,
        float* __restrict__ gsum, float* __restrict__ gsq) {
    __shared__ float lsum[NB * G];
    __shared__ float lsq [NB * G];
    __shared__ int   soff[NB + 1];
    const int t = threadIdx.x;
    if (t < NB * G) { lsum[t] = 0.f; lsq[t] = 0.f; }
    if (t < NB + 1) soff[t] = off_g[t];
    __syncthreads();

    const int rpb  = (n + GRID - 1) / GRID;
    const int row0 = (int)blockIdx.x * rpb;
    const int row1 = min(n, row0 + rpb);

    if (row0 < row1) {
        const int quad   = t & 15;
        const int subrow = t >> 4;
        const int lane   = t & 63;
        int b = 0, cur = row0;
        while (cur < row1) {
            while (soff[b + 1] <= cur) ++b;          // batch of this segment
            const int send = min(row1, soff[b + 1]); // segment end (block-uniform)
            float s0=0.f,s1=0.f,s2=0.f,s3=0.f,q0=0.f,q1=0.f,q2=0.f,q3=0.f;
            const float* p = feats + (size_t)(cur + subrow) * F + quad * 4;
            int base = cur;
            #pragma unroll 4
            for (; base + 16 <= send; base += 16, p += 16 * F) {
                const float4 x = *reinterpret_cast<const float4*>(p);
                s0 += x.x; q0 = fmaf(x.x, x.x, q0);
                s1 += x.y; q1 = fmaf(x.y, x.y, q1);
                s2 += x.z; q2 = fmaf(x.z, x.z, q2);
                s3 += x.w; q3 = fmaf(x.w, x.w, q3);
            }
            if (base + subrow < send) {              // segment tail (<16 rows)
                const float4 x = *reinterpret_cast<const float4*>(p);
                s0 += x.x; q0 = fmaf(x.x, x.x, q0);
                s1 += x.y; q1 = fmaf(x.y, x.y, q1);
                s2 += x.z; q2 = fmaf(x.z, x.z, q2);
                s3 += x.w; q3 = fmaf(x.w, x.w, q3);
            }
            // butterfly over lane-bits 1..5: lanes with equal (lane&1) merge,
            // so lane0 holds groups 0..3 totals, lane1 holds groups 4..7.
            #pragma unroll
            for (int m = 2; m <= 32; m <<= 1) {
                s0 += __shfl_xor(s0, m); s1 += __shfl_xor(s1, m);
                s2 += __shfl_xor(s2, m); s3 += __shfl_xor(s3, m);
                q0 += __shfl_xor(q0, m); q1 += __shfl_xor(q1, m);
                q2 += __shfl_xor(q2, m); q3 += __shfl_xor(q3, m);
            }
            if (lane < 2) {
                float* ps = &lsum[b * G + lane * 4];
                float* pq = &lsq [b * G + lane * 4];
                atomicAdd(ps + 0, s0); atomicAdd(ps + 1, s1);
                atomicAdd(ps + 2, s2); atomicAdd(ps + 3, s3);
                atomicAdd(pq + 0, q0); atomicAdd(pq + 1, q1);
                atomicAdd(pq + 2, q2); atomicAdd(pq + 3, q3);
            }
            cur = send;
        }
    }
    __syncthreads();
    if (t < NB * G) {
        atomicAdd(&gsum[t], lsum[t]);
        atomicAdd(&gsq [t], lsq [t]);
    }
}

// --- Kernel C: normalize. Per-segment coefficients live in registers; the hot
// loop is load float4 -> 4 fma -> nontemporal store (out is never re-read, and
// nt keeps the 256MB output from evicting feats out of the 256MB L3). ---
__global__ __launch_bounds__(BLK) void gn_norm(
        const float* __restrict__ feats, const int* __restrict__ off_g, int n,
        const float* __restrict__ gsum, const float* __restrict__ gsq,
        const float* __restrict__ gamma, const float* __restrict__ beta,
        float* __restrict__ out) {
    __shared__ int soff[NB + 1];
    const int t = threadIdx.x;
    if (t < NB + 1) soff[t] = off_g[t];
    __syncthreads();

    const int rpb  = (n + GRID - 1) / GRID;
    const int row0 = (int)blockIdx.x * rpb;
    const int row1 = min(n, row0 + rpb);
    if (row0 >= row1) return;

    const int quad   = t & 15;
    const int subrow = t >> 4;
    const float4 gm = *reinterpret_cast<const float4*>(gamma + quad * 4);
    const float4 bt = *reinterpret_cast<const float4*>(beta  + quad * 4);

    int b = 0, cur = row0;
    while (cur < row1) {
        while (soff[b + 1] <= cur) ++b;
        const int send = min(row1, soff[b + 1]);
        // per-segment coefficients: this lane's 4 channels map to groups
        // (quad&1)*4 .. +3  -> an aligned float4 of gsum/gsq.
        const float4 sm = *reinterpret_cast<const float4*>(gsum + b * G + (quad & 1) * 4);
        const float4 sq = *reinterpret_cast<const float4*>(gsq  + b * G + (quad & 1) * 4);
        const float cnt = (float)max((soff[b + 1] - soff[b]) * (F / G), 1);
        const float rc  = 1.0f / cnt;
        float4 a, c;
        {
            const float m0 = sm.x * rc, m1 = sm.y * rc, m2 = sm.z * rc, m3 = sm.w * rc;
            const float v0 = fmaxf(sq.x * rc - m0 * m0, 0.f);
            const float v1 = fmaxf(sq.y * rc - m1 * m1, 0.f);
            const float v2 = fmaxf(sq.z * rc - m2 * m2, 0.f);
            const float v3 = fmaxf(sq.w * rc - m3 * m3, 0.f);
            a.x = gm.x / sqrtf(v0 + GN_EPS); a.y = gm.y / sqrtf(v1 + GN_EPS);
            a.z = gm.z / sqrtf(v2 + GN_EPS); a.w = gm.w / sqrtf(v3 + GN_EPS);
            c.x = fmaf(-m0, a.x, bt.x); c.y = fmaf(-m1, a.y, bt.y);
            c.z = fmaf(-m2, a.z, bt.z); c.w = fmaf(-m3, a.w, bt.w);
        }
        const float* p  = feats + (size_t)(cur + subrow) * F + quad * 4;
        float*       po = out   + (size_t)(cur + subrow) * F + quad * 4;
        int base = cur;
        #pragma unroll 4
        for (; base + 16 <= send; base += 16, p += 16 * F, po += 16 * F) {
            const float4 x = *reinterpret_cast<const float4*>(p);
            f32x4 o;
            o.x = fmaf(x.x, a.x, c.x); o.y = fmaf(x.y, a.y, c.y);
            o.z = fmaf(x.z, a.z, c.z); o.w = fmaf(x.w, a.w, c.w);
            __builtin_nontemporal_store(o, reinterpret_cast<f32x4*>(po));
        }
        if (base + subrow < send) {
            const float4 x = *reinterpret_cast<const float4*>(p);
            f32x4 o;
            o.x = fmaf(x.x, a.x, c.x); o.y = fmaf(x.y, a.y, c.y);
            o.z = fmaf(x.z, a.z, c.z); o.w = fmaf(x.w, a.w, c.w);
            __builtin_nontemporal_store(o, reinterpret_cast<f32x4*>(po));
        }
        cur = send;
    }
}

extern "C" void kernel_launch(void* const* d_in, const int* in_sizes, int n_in,
                              void* d_out, int out_size, void* d_ws, size_t ws_size,
                              hipStream_t stream) {
    const float* feats = (const float*)d_in[0];
    const int*   ids   = (const int*)  d_in[1];
    const float* gamma = (const float*)d_in[2];
    const float* beta  = (const float*)d_in[3];
    const int n = in_sizes[1];               // N rows (batch_ids count)

    float* gsum = (float*)d_ws;              // [NB*G]
    float* gsq  = gsum + NB * G;             // [NB*G]
    int*   off  = (int*)(gsq + NB * G);      // [NB+1]

    // ws is poisoned 0xAA and never re-poisoned between replays -> zero the accumulators.
    hipMemsetAsync(d_ws, 0, 2 * NB * G * sizeof(float), stream);
    gn_offsets<<<1, 32, 0, stream>>>(ids, n, off);
    gn_stats  <<<GRID, BLK, 0, stream>>>(feats, off, n, gsum, gsq);
    gn_norm   <<<GRID, BLK, 0, stream>>>(feats, off, n, gsum, gsq, gamma, beta, (float*)d_out);
}

// Round 3
// 156.497 us; speedup vs baseline: 1.1416x; 1.0420x over previous
//
#include <hip/hip_runtime.h>

#define GN_EPS 1e-8f

static constexpr int F    = 64;   // features
static constexpr int G    = 8;    // groups (group of channel f is f & 7 due to reshape(-1, G))
static constexpr int NB   = 16;   // batches
static constexpr int BLK  = 256;
static constexpr int GRID = 2048; // 2048 blocks x 4 waves = 8192 waves = full residency

typedef float f32x4 __attribute__((ext_vector_type(4)));

// --- Kernel A: zero accumulators + per-batch offsets (binary search; ids sorted) ---
__global__ void gn_prep(const int* __restrict__ ids, int n, int* __restrict__ off,
                        float* __restrict__ zbuf /* gsum||gsq, 2*NB*G floats */) {
    const int t = threadIdx.x;
    if (t < 2 * NB * G) zbuf[t] = 0.f;
    if (t < NB + 1) {
        int lo = 0, hi = n;
        while (lo < hi) {
            int mid = (lo + hi) >> 1;
            if (ids[mid] < t) lo = mid + 1; else hi = mid;
        }
        off[t] = lo;   // off[b] = first row with id >= b; off[0]=0, off[NB]=n
    }
}

// --- Kernel B: per-(batch,group) sum/sumsq, segment-uniform inner loop ---
// 16 threads/row (float4 each); 32-row tiles: each lane handles rows subrow and
// subrow+16 (2 independent loads in flight, x2 with unroll). Element j of the
// float4 at feature quad*4+j belongs to group (quad&1)*4 + j.
__global__ __launch_bounds__(BLK) void gn_stats(
        const float* __restrict__ feats, const int* __restrict__ off_g, int n,
        float* __restrict__ gsum, float* __restrict__ gsq) {
    __shared__ float lsum[NB * G];
    __shared__ float lsq [NB * G];
    __shared__ int   soff[NB + 1];
    const int t = threadIdx.x;
    if (t < NB * G) { lsum[t] = 0.f; lsq[t] = 0.f; }
    if (t < NB + 1) soff[t] = off_g[t];
    __syncthreads();

    const int rpb  = (n + GRID - 1) / GRID;
    const int row0 = (int)blockIdx.x * rpb;
    const int row1 = min(n, row0 + rpb);

    if (row0 < row1) {
        const int quad   = t & 15;
        const int subrow = t >> 4;
        const int lane   = t & 63;
        int b = 0, cur = row0;
        while (cur < row1) {
            while (soff[b + 1] <= cur) ++b;          // batch of this segment
            const int send = min(row1, soff[b + 1]); // segment end (block-uniform)
            float s0=0.f,s1=0.f,s2=0.f,s3=0.f,q0=0.f,q1=0.f,q2=0.f,q3=0.f;
            const float* p = feats + (size_t)(cur + subrow) * F + quad * 4;
            int base = cur;
            #pragma unroll 2
            for (; base + 32 <= send; base += 32, p += 32 * F) {
                const float4 x0 = *reinterpret_cast<const float4*>(p);
                const float4 x1 = *reinterpret_cast<const float4*>(p + 16 * F);
                s0 += x0.x; q0 = fmaf(x0.x, x0.x, q0);
                s1 += x0.y; q1 = fmaf(x0.y, x0.y, q1);
                s2 += x0.z; q2 = fmaf(x0.z, x0.z, q2);
                s3 += x0.w; q3 = fmaf(x0.w, x0.w, q3);
                s0 += x1.x; q0 = fmaf(x1.x, x1.x, q0);
                s1 += x1.y; q1 = fmaf(x1.y, x1.y, q1);
                s2 += x1.z; q2 = fmaf(x1.z, x1.z, q2);
                s3 += x1.w; q3 = fmaf(x1.w, x1.w, q3);
            }
            if (base + 16 <= send) {
                const float4 x = *reinterpret_cast<const float4*>(p);
                s0 += x.x; q0 = fmaf(x.x, x.x, q0);
                s1 += x.y; q1 = fmaf(x.y, x.y, q1);
                s2 += x.z; q2 = fmaf(x.z, x.z, q2);
                s3 += x.w; q3 = fmaf(x.w, x.w, q3);
                base += 16; p += 16 * F;
            }
            if (base + subrow < send) {              // segment tail (<16 rows)
                const float4 x = *reinterpret_cast<const float4*>(p);
                s0 += x.x; q0 = fmaf(x.x, x.x, q0);
                s1 += x.y; q1 = fmaf(x.y, x.y, q1);
                s2 += x.z; q2 = fmaf(x.z, x.z, q2);
                s3 += x.w; q3 = fmaf(x.w, x.w, q3);
            }
            // butterfly over lane-bits 1..5: lanes with equal (lane&1) merge,
            // so lane0 holds groups 0..3 totals, lane1 holds groups 4..7.
            #pragma unroll
            for (int m = 2; m <= 32; m <<= 1) {
                s0 += __shfl_xor(s0, m); s1 += __shfl_xor(s1, m);
                s2 += __shfl_xor(s2, m); s3 += __shfl_xor(s3, m);
                q0 += __shfl_xor(q0, m); q1 += __shfl_xor(q1, m);
                q2 += __shfl_xor(q2, m); q3 += __shfl_xor(q3, m);
            }
            if (lane < 2) {
                float* ps = &lsum[b * G + lane * 4];
                float* pq = &lsq [b * G + lane * 4];
                atomicAdd(ps + 0, s0); atomicAdd(ps + 1, s1);
                atomicAdd(ps + 2, s2); atomicAdd(ps + 3, s3);
                atomicAdd(pq + 0, q0); atomicAdd(pq + 1, q1);
                atomicAdd(pq + 2, q2); atomicAdd(pq + 3, q3);
            }
            cur = send;
        }
    }
    __syncthreads();
    if (t < NB * G) {
        atomicAdd(&gsum[t], lsum[t]);
        atomicAdd(&gsq [t], lsq [t]);
    }
}

// --- Kernel C: normalize. Per-segment coefficients in registers; hot loop is
// nt-load float4 -> 4 fma -> nt-store. nt loads: last use of feats, evict-first
// frees L3 as we consume; nt stores: keep out from evicting feats out of L3. ---
__global__ __launch_bounds__(BLK) void gn_norm(
        const float* __restrict__ feats, const int* __restrict__ off_g, int n,
        const float* __restrict__ gsum, const float* __restrict__ gsq,
        const float* __restrict__ gamma, const float* __restrict__ beta,
        float* __restrict__ out) {
    __shared__ int soff[NB + 1];
    const int t = threadIdx.x;
    if (t < NB + 1) soff[t] = off_g[t];
    __syncthreads();

    const int rpb  = (n + GRID - 1) / GRID;
    const int row0 = (int)blockIdx.x * rpb;
    const int row1 = min(n, row0 + rpb);
    if (row0 >= row1) return;

    const int quad   = t & 15;
    const int subrow = t >> 4;
    const float4 gm = *reinterpret_cast<const float4*>(gamma + quad * 4);
    const float4 bt = *reinterpret_cast<const float4*>(beta  + quad * 4);

    int b = 0, cur = row0;
    while (cur < row1) {
        while (soff[b + 1] <= cur) ++b;
        const int send = min(row1, soff[b + 1]);
        // this lane's 4 channels map to groups (quad&1)*4 .. +3
        const float4 sm = *reinterpret_cast<const float4*>(gsum + b * G + (quad & 1) * 4);
        const float4 sq = *reinterpret_cast<const float4*>(gsq  + b * G + (quad & 1) * 4);
        const float cnt = (float)max((soff[b + 1] - soff[b]) * (F / G), 1);
        const float rc  = 1.0f / cnt;
        f32x4 a, c;
        {
            const float m0 = sm.x * rc, m1 = sm.y * rc, m2 = sm.z * rc, m3 = sm.w * rc;
            const float v0 = fmaxf(sq.x * rc - m0 * m0, 0.f);
            const float v1 = fmaxf(sq.y * rc - m1 * m1, 0.f);
            const float v2 = fmaxf(sq.z * rc - m2 * m2, 0.f);
            const float v3 = fmaxf(sq.w * rc - m3 * m3, 0.f);
            a.x = gm.x / sqrtf(v0 + GN_EPS); a.y = gm.y / sqrtf(v1 + GN_EPS);
            a.z = gm.z / sqrtf(v2 + GN_EPS); a.w = gm.w / sqrtf(v3 + GN_EPS);
            c.x = fmaf(-m0, a.x, bt.x); c.y = fmaf(-m1, a.y, bt.y);
            c.z = fmaf(-m2, a.z, bt.z); c.w = fmaf(-m3, a.w, bt.w);
        }
        const float* p  = feats + (size_t)(cur + subrow) * F + quad * 4;
        float*       po = out   + (size_t)(cur + subrow) * F + quad * 4;
        int base = cur;
        #pragma unroll 2
        for (; base + 32 <= send; base += 32, p += 32 * F, po += 32 * F) {
            const f32x4 x0 = __builtin_nontemporal_load(reinterpret_cast<const f32x4*>(p));
            const f32x4 x1 = __builtin_nontemporal_load(reinterpret_cast<const f32x4*>(p + 16 * F));
            f32x4 o0, o1;
            o0.x = fmaf(x0.x, a.x, c.x); o0.y = fmaf(x0.y, a.y, c.y);
            o0.z = fmaf(x0.z, a.z, c.z); o0.w = fmaf(x0.w, a.w, c.w);
            o1.x = fmaf(x1.x, a.x, c.x); o1.y = fmaf(x1.y, a.y, c.y);
            o1.z = fmaf(x1.z, a.z, c.z); o1.w = fmaf(x1.w, a.w, c.w);
            __builtin_nontemporal_store(o0, reinterpret_cast<f32x4*>(po));
            __builtin_nontemporal_store(o1, reinterpret_cast<f32x4*>(po + 16 * F));
        }
        if (base + 16 <= send) {
            const f32x4 x = __builtin_nontemporal_load(reinterpret_cast<const f32x4*>(p));
            f32x4 o;
            o.x = fmaf(x.x, a.x, c.x); o.y = fmaf(x.y, a.y, c.y);
            o.z = fmaf(x.z, a.z, c.z); o.w = fmaf(x.w, a.w, c.w);
            __builtin_nontemporal_store(o, reinterpret_cast<f32x4*>(po));
            base += 16; p += 16 * F; po += 16 * F;
        }
        if (base + subrow < send) {
            const f32x4 x = __builtin_nontemporal_load(reinterpret_cast<const f32x4*>(p));
            f32x4 o;
            o.x = fmaf(x.x, a.x, c.x); o.y = fmaf(x.y, a.y, c.y);
            o.z = fmaf(x.z, a.z, c.z); o.w = fmaf(x.w, a.w, c.w);
            __builtin_nontemporal_store(o, reinterpret_cast<f32x4*>(po));
        }
        cur = send;
    }
}

extern "C" void kernel_launch(void* const* d_in, const int* in_sizes, int n_in,
                              void* d_out, int out_size, void* d_ws, size_t ws_size,
                              hipStream_t stream) {
    const float* feats = (const float*)d_in[0];
    const int*   ids   = (const int*)  d_in[1];
    const float* gamma = (const float*)d_in[2];
    const float* beta  = (const float*)d_in[3];
    const int n = in_sizes[1];               // N rows (batch_ids count)

    float* gsum = (float*)d_ws;              // [NB*G]
    float* gsq  = gsum + NB * G;             // [NB*G]
    int*   off  = (int*)(gsq + NB * G);      // [NB+1]

    // ws is poisoned 0xAA and never re-poisoned between replays -> prep zeroes the
    // accumulators and builds the offset table in a single tiny dispatch.
    gn_prep <<<1, BLK, 0, stream>>>(ids, n, off, gsum);
    gn_stats<<<GRID, BLK, 0, stream>>>(feats, off, n, gsum, gsq);
    gn_norm <<<GRID, BLK, 0, stream>>>(feats, off, n, gsum, gsq, gamma, beta, (float*)d_out);
}

// Round 4
// 132.514 us; speedup vs baseline: 1.3483x; 1.1810x over previous
//
#include <hip/hip_runtime.h>

#define GN_EPS 1e-8f

static constexpr int F     = 64;   // features
static constexpr int G     = 8;    // groups (group of channel f is f & 7 due to reshape(-1, G))
static constexpr int NB    = 16;   // batches
static constexpr int BLK   = 256;
static constexpr int GRID  = 2048; // 2048 blocks x 4 waves = full residency
static constexpr int NSLOT = 16;   // shadow accumulator copies (atomic contention 2048 -> 128)

typedef float f32x4 __attribute__((ext_vector_type(4)));

// ws layout: gsum[NSLOT][NB*G] | gsq[NSLOT][NB*G] | off[NB+1]

// --- Kernel A: zero shadow accumulators + per-batch offsets (ids sorted) ---
__global__ void gn_prep(const int* __restrict__ ids, int n, int* __restrict__ off,
                        float* __restrict__ zbuf /* 2*NSLOT*NB*G floats */) {
    const int t = threadIdx.x;
    for (int i = t; i < 2 * NSLOT * NB * G; i += BLK) zbuf[i] = 0.f;
    if (t < NB + 1) {
        int lo = 0, hi = n;
        while (lo < hi) {
            int mid = (lo + hi) >> 1;
            if (ids[mid] < t) lo = mid + 1; else hi = mid;
        }
        off[t] = lo;   // off[b] = first row with id >= b; off[0]=0, off[NB]=n
    }
}

// --- Kernel B: per-(batch,group) sum/sumsq, segment-uniform inner loop ---
// 16 threads/row (float4 each); 64-row tiles = 4 independent loads/lane/iter.
// Element j of the float4 at feature quad*4+j belongs to group (quad&1)*4 + j.
// Regular (caching) loads on purpose: this pass warms L3 for gn_norm.
__global__ __launch_bounds__(BLK) void gn_stats(
        const float* __restrict__ feats, const int* __restrict__ off_g, int n,
        float* __restrict__ gsum, float* __restrict__ gsq) {
    __shared__ float lsum[NB * G];
    __shared__ float lsq [NB * G];
    __shared__ int   soff[NB + 1];
    const int t = threadIdx.x;
    if (t < NB * G) { lsum[t] = 0.f; lsq[t] = 0.f; }
    if (t < NB + 1) soff[t] = off_g[t];
    __syncthreads();

    const int rpb  = (n + GRID - 1) / GRID;
    const int row0 = (int)blockIdx.x * rpb;
    const int row1 = min(n, row0 + rpb);

    if (row0 < row1) {
        const int quad   = t & 15;
        const int subrow = t >> 4;
        const int lane   = t & 63;
        int b = 0, cur = row0;
        while (cur < row1) {
            while (soff[b + 1] <= cur) ++b;          // batch of this segment
            const int send = min(row1, soff[b + 1]); // segment end (block-uniform)
            float s0=0.f,s1=0.f,s2=0.f,s3=0.f,q0=0.f,q1=0.f,q2=0.f,q3=0.f;
            const float* p = feats + (size_t)(cur + subrow) * F + quad * 4;
            int base = cur;
            for (; base + 64 <= send; base += 64, p += 64 * F) {
                const float4 x0 = *reinterpret_cast<const float4*>(p);
                const float4 x1 = *reinterpret_cast<const float4*>(p + 16 * F);
                const float4 x2 = *reinterpret_cast<const float4*>(p + 32 * F);
                const float4 x3 = *reinterpret_cast<const float4*>(p + 48 * F);
                s0 += x0.x; q0 = fmaf(x0.x, x0.x, q0);
                s1 += x0.y; q1 = fmaf(x0.y, x0.y, q1);
                s2 += x0.z; q2 = fmaf(x0.z, x0.z, q2);
                s3 += x0.w; q3 = fmaf(x0.w, x0.w, q3);
                s0 += x1.x; q0 = fmaf(x1.x, x1.x, q0);
                s1 += x1.y; q1 = fmaf(x1.y, x1.y, q1);
                s2 += x1.z; q2 = fmaf(x1.z, x1.z, q2);
                s3 += x1.w; q3 = fmaf(x1.w, x1.w, q3);
                s0 += x2.x; q0 = fmaf(x2.x, x2.x, q0);
                s1 += x2.y; q1 = fmaf(x2.y, x2.y, q1);
                s2 += x2.z; q2 = fmaf(x2.z, x2.z, q2);
                s3 += x2.w; q3 = fmaf(x2.w, x2.w, q3);
                s0 += x3.x; q0 = fmaf(x3.x, x3.x, q0);
                s1 += x3.y; q1 = fmaf(x3.y, x3.y, q1);
                s2 += x3.z; q2 = fmaf(x3.z, x3.z, q2);
                s3 += x3.w; q3 = fmaf(x3.w, x3.w, q3);
            }
            for (; base + 16 <= send; base += 16, p += 16 * F) {
                const float4 x = *reinterpret_cast<const float4*>(p);
                s0 += x.x; q0 = fmaf(x.x, x.x, q0);
                s1 += x.y; q1 = fmaf(x.y, x.y, q1);
                s2 += x.z; q2 = fmaf(x.z, x.z, q2);
                s3 += x.w; q3 = fmaf(x.w, x.w, q3);
            }
            if (base + subrow < send) {              // segment tail (<16 rows)
                const float4 x = *reinterpret_cast<const float4*>(p);
                s0 += x.x; q0 = fmaf(x.x, x.x, q0);
                s1 += x.y; q1 = fmaf(x.y, x.y, q1);
                s2 += x.z; q2 = fmaf(x.z, x.z, q2);
                s3 += x.w; q3 = fmaf(x.w, x.w, q3);
            }
            // butterfly over lane-bits 1..5: lanes with equal (lane&1) merge,
            // so lane0 holds groups 0..3 totals, lane1 holds groups 4..7.
            #pragma unroll
            for (int m = 2; m <= 32; m <<= 1) {
                s0 += __shfl_xor(s0, m); s1 += __shfl_xor(s1, m);
                s2 += __shfl_xor(s2, m); s3 += __shfl_xor(s3, m);
                q0 += __shfl_xor(q0, m); q1 += __shfl_xor(q1, m);
                q2 += __shfl_xor(q2, m); q3 += __shfl_xor(q3, m);
            }
            if (lane < 2) {
                float* ps = &lsum[b * G + lane * 4];
                float* pq = &lsq [b * G + lane * 4];
                atomicAdd(ps + 0, s0); atomicAdd(ps + 1, s1);
                atomicAdd(ps + 2, s2); atomicAdd(ps + 3, s3);
                atomicAdd(pq + 0, q0); atomicAdd(pq + 1, q1);
                atomicAdd(pq + 2, q2); atomicAdd(pq + 3, q3);
            }
            cur = send;
        }
    }
    __syncthreads();
    if (t < NB * G) {
        const int slot = (int)blockIdx.x & (NSLOT - 1);
        atomicAdd(&gsum[slot * NB * G + t], lsum[t]);
        atomicAdd(&gsq [slot * NB * G + t], lsq [t]);
    }
}

// --- Kernel C: normalize, REVERSED traversal. Stats walked forward; L3 (256MB)
// holds feats but norm's 256MB output stream evicts it under LRU. Walking
// backward consumes lines in reverse-recency order (most-recently-cached first)
// and also hits the L2 tails stats left on each XCD. nt-load: evict-first after
// last use; nt-store: discourage output from allocating over feats. ---
__global__ __launch_bounds__(BLK) void gn_norm(
        const float* __restrict__ feats, const int* __restrict__ off_g, int n,
        const float* __restrict__ gsum, const float* __restrict__ gsq,
        const float* __restrict__ gamma, const float* __restrict__ beta,
        float* __restrict__ out) {
    __shared__ int soff[NB + 1];
    const int t = threadIdx.x;
    if (t < NB + 1) soff[t] = off_g[t];
    __syncthreads();

    const int rpb  = (n + GRID - 1) / GRID;
    const int row0 = (int)blockIdx.x * rpb;
    const int row1 = min(n, row0 + rpb);
    if (row0 >= row1) return;

    const int quad   = t & 15;
    const int subrow = t >> 4;
    const float4 gm = *reinterpret_cast<const float4*>(gamma + quad * 4);
    const float4 bt = *reinterpret_cast<const float4*>(beta  + quad * 4);

    int b = NB - 1, e = row1;
    while (e > row0) {
        while (soff[b] >= e) --b;                 // rows e-1 belong to batch b
        const int sstart = max(row0, soff[b]);    // segment = [sstart, e), uniform b
        // sum the NSLOT shadow copies for this lane's 4 groups ((quad&1)*4 ..+3)
        f32x4 sm = {0.f, 0.f, 0.f, 0.f}, sq = {0.f, 0.f, 0.f, 0.f};
        #pragma unroll
        for (int k = 0; k < NSLOT; ++k) {
            sm += *reinterpret_cast<const f32x4*>(gsum + k * NB * G + b * G + (quad & 1) * 4);
            sq += *reinterpret_cast<const f32x4*>(gsq  + k * NB * G + b * G + (quad & 1) * 4);
        }
        const float cnt = (float)max((soff[b + 1] - soff[b]) * (F / G), 1);
        const float rc  = 1.0f / cnt;
        f32x4 a, c;
        {
            const float m0 = sm.x * rc, m1 = sm.y * rc, m2 = sm.z * rc, m3 = sm.w * rc;
            const float v0 = fmaxf(sq.x * rc - m0 * m0, 0.f);
            const float v1 = fmaxf(sq.y * rc - m1 * m1, 0.f);
            const float v2 = fmaxf(sq.z * rc - m2 * m2, 0.f);
            const float v3 = fmaxf(sq.w * rc - m3 * m3, 0.f);
            a.x = gm.x / sqrtf(v0 + GN_EPS); a.y = gm.y / sqrtf(v1 + GN_EPS);
            a.z = gm.z / sqrtf(v2 + GN_EPS); a.w = gm.w / sqrtf(v3 + GN_EPS);
            c.x = fmaf(-m0, a.x, bt.x); c.y = fmaf(-m1, a.y, bt.y);
            c.z = fmaf(-m2, a.z, bt.z); c.w = fmaf(-m3, a.w, bt.w);
        }
        int hi = e;
        for (; hi - sstart >= 64; hi -= 64) {     // 64-row tiles, descending
            const float* p  = feats + (size_t)(hi - 64 + subrow) * F + quad * 4;
            float*       po = out   + (size_t)(hi - 64 + subrow) * F + quad * 4;
            const f32x4 x0 = __builtin_nontemporal_load(reinterpret_cast<const f32x4*>(p));
            const f32x4 x1 = __builtin_nontemporal_load(reinterpret_cast<const f32x4*>(p + 16 * F));
            const f32x4 x2 = __builtin_nontemporal_load(reinterpret_cast<const f32x4*>(p + 32 * F));
            const f32x4 x3 = __builtin_nontemporal_load(reinterpret_cast<const f32x4*>(p + 48 * F));
            f32x4 o0, o1, o2, o3;
            o0.x = fmaf(x0.x, a.x, c.x); o0.y = fmaf(x0.y, a.y, c.y);
            o0.z = fmaf(x0.z, a.z, c.z); o0.w = fmaf(x0.w, a.w, c.w);
            o1.x = fmaf(x1.x, a.x, c.x); o1.y = fmaf(x1.y, a.y, c.y);
            o1.z = fmaf(x1.z, a.z, c.z); o1.w = fmaf(x1.w, a.w, c.w);
            o2.x = fmaf(x2.x, a.x, c.x); o2.y = fmaf(x2.y, a.y, c.y);
            o2.z = fmaf(x2.z, a.z, c.z); o2.w = fmaf(x2.w, a.w, c.w);
            o3.x = fmaf(x3.x, a.x, c.x); o3.y = fmaf(x3.y, a.y, c.y);
            o3.z = fmaf(x3.z, a.z, c.z); o3.w = fmaf(x3.w, a.w, c.w);
            __builtin_nontemporal_store(o0, reinterpret_cast<f32x4*>(po));
            __builtin_nontemporal_store(o1, reinterpret_cast<f32x4*>(po + 16 * F));
            __builtin_nontemporal_store(o2, reinterpret_cast<f32x4*>(po + 32 * F));
            __builtin_nontemporal_store(o3, reinterpret_cast<f32x4*>(po + 48 * F));
        }
        for (; hi - sstart >= 16; hi -= 16) {     // 16-row tiles, descending
            const float* p  = feats + (size_t)(hi - 16 + subrow) * F + quad * 4;
            float*       po = out   + (size_t)(hi - 16 + subrow) * F + quad * 4;
            const f32x4 x = __builtin_nontemporal_load(reinterpret_cast<const f32x4*>(p));
            f32x4 o;
            o.x = fmaf(x.x, a.x, c.x); o.y = fmaf(x.y, a.y, c.y);
            o.z = fmaf(x.z, a.z, c.z); o.w = fmaf(x.w, a.w, c.w);
            __builtin_nontemporal_store(o, reinterpret_cast<f32x4*>(po));
        }
        if (sstart + subrow < hi) {               // bottom tail (<16 rows)
            const float* p  = feats + (size_t)(sstart + subrow) * F + quad * 4;
            float*       po = out   + (size_t)(sstart + subrow) * F + quad * 4;
            const f32x4 x = __builtin_nontemporal_load(reinterpret_cast<const f32x4*>(p));
            f32x4 o;
            o.x = fmaf(x.x, a.x, c.x); o.y = fmaf(x.y, a.y, c.y);
            o.z = fmaf(x.z, a.z, c.z); o.w = fmaf(x.w, a.w, c.w);
            __builtin_nontemporal_store(o, reinterpret_cast<f32x4*>(po));
        }
        e = sstart;
    }
}

extern "C" void kernel_launch(void* const* d_in, const int* in_sizes, int n_in,
                              void* d_out, int out_size, void* d_ws, size_t ws_size,
                              hipStream_t stream) {
    const float* feats = (const float*)d_in[0];
    const int*   ids   = (const int*)  d_in[1];
    const float* gamma = (const float*)d_in[2];
    const float* beta  = (const float*)d_in[3];
    const int n = in_sizes[1];                     // N rows (batch_ids count)

    float* gsum = (float*)d_ws;                    // [NSLOT][NB*G]
    float* gsq  = gsum + NSLOT * NB * G;           // [NSLOT][NB*G]
    int*   off  = (int*)(gsq + NSLOT * NB * G);    // [NB+1]

    // ws is poisoned 0xAA and never re-poisoned between replays -> prep zeroes
    // the shadow accumulators and builds the offset table each call.
    gn_prep <<<1, BLK, 0, stream>>>(ids, n, off, gsum);
    gn_stats<<<GRID, BLK, 0, stream>>>(feats, off, n, gsum, gsq);
    gn_norm <<<GRID, BLK, 0, stream>>>(feats, off, n, gsum, gsq, gamma, beta, (float*)d_out);
}